// Round 17
// baseline (732.224 us; speedup 1.0000x reference)
//
#include <hip/hip_runtime.h>
#include <hip/hip_cooperative_groups.h>
#include <math.h>

namespace cg = cooperative_groups;

#define ROUTIT 6
#define CAPQ 5   // cached quartet-steps per wave (+1 pad slot for prefetch)
#define WPB 2    // waves per block in route_kernel
#define SCB 256  // cooperative CSR grid blocks

__device__ __forceinline__ int load_idx(const void* p, long long i, int is64)
{
    if (is64) return (int)((const long long*)p)[i];
    return ((const int*)p)[i];
}

// ---------------------------------------------------------------------------
// DPP helpers (VALU pipe) — verified r8-16.
// ---------------------------------------------------------------------------
template <int CTRL>
__device__ __forceinline__ float dpp_add(float x)
{
    int y = __builtin_amdgcn_update_dpp(0, __float_as_int(x), CTRL, 0xf, 0xf, true);
    return x + __int_as_float(y);
}

__device__ __forceinline__ float grpsum4(float p)
{
    p = dpp_add<0xB1>(p);   // quad_perm xor1
    p = dpp_add<0x4E>(p);   // quad_perm xor2
    return p;
}

__device__ __forceinline__ float rowtotal16(float x)
{
    x = dpp_add<0x124>(x);  // row_ror:4
    x = dpp_add<0x128>(x);  // row_ror:8
    return x;
}

__device__ __forceinline__ float sum_x16(float x)
{
#if __has_builtin(__builtin_amdgcn_permlane16_swap)
    unsigned u = __float_as_uint(x);
    auto r = __builtin_amdgcn_permlane16_swap(u, u, false, false);
    return __uint_as_float(r[0]) + __uint_as_float(r[1]);
#else
    return x + __shfl_xor(x, 16);
#endif
}

__device__ __forceinline__ float sum_x32(float x)
{
#if __has_builtin(__builtin_amdgcn_permlane32_swap)
    unsigned u = __float_as_uint(x);
    auto r = __builtin_amdgcn_permlane32_swap(u, u, false, false);
    return __uint_as_float(r[0]) + __uint_as_float(r[1]);
#else
    return x + __shfl_xor(x, 32);
#endif
}

// per-quartet-step (verified r15/16). Dummy edges (z=0) are inert.
__device__ __forceinline__ void quad_acc(const float4& zA, const float4& zB,
                                         const float4& cA, const float4& cB,
                                         float4& aA, float4& aB)
{
    float p = zA.x*cA.x + zA.y*cA.y + zA.z*cA.z + zA.w*cA.w
            + zB.x*cB.x + zB.y*cB.y + zB.z*cB.z + zB.w*cB.w;
    p = grpsum4(p);                     // 32-dim channel dot, |p| <= 1
    float ex = __expf(p);
    float d  = rowtotal16(ex);          // softmax denom (4 channels, in-row)
    float w  = ex * __builtin_amdgcn_rcpf(d);
    aA.x += w * zA.x;  aA.y += w * zA.y;  aA.z += w * zA.z;  aA.w += w * zA.w;
    aB.x += w * zB.x;  aB.y += w * zB.y;  aB.z += w * zB.z;  aB.w += w * zB.w;
}

// ---------------------------------------------------------------------------
// GEMM + per-channel L2 normalize (fp32 h) — round-13 v3 (kept).
// ---------------------------------------------------------------------------
__global__ __launch_bounds__(256)
void gemm_norm_kernel(const float* __restrict__ x, const float* __restrict__ W,
                      const float* __restrict__ b, float* __restrict__ h, int n)
{
    __shared__ float WT[32 * 132];    // WT[lc*132 + j] = W[j][l0+lc]

    const int tid  = threadIdx.x;
    const int jc   = tid & 31;
    const int rg   = tid >> 5;
    const int row0 = blockIdx.x * 32;

    float4 bb = ((const float4*)b)[jc];
    float acc[4][4];
    #pragma unroll
    for (int ri = 0; ri < 4; ++ri) {
        acc[ri][0] = bb.x; acc[ri][1] = bb.y; acc[ri][2] = bb.z; acc[ri][3] = bb.w;
    }

    for (int l0 = 0; l0 < 128; l0 += 32) {
        __syncthreads();
        for (int t = 0; t < 16; ++t) {
            int idx = t * 256 + tid;
            int j = idx >> 5, lc = idx & 31;
            WT[lc * 132 + j] = W[j * 128 + l0 + lc];
        }
        __syncthreads();

        #pragma unroll 2
        for (int q = 0; q < 8; ++q) {
            float4 xq[4];
            #pragma unroll
            for (int ri = 0; ri < 4; ++ri) {
                int row = row0 + rg * 4 + ri;
                row = row < n ? row : n - 1;
                xq[ri] = *(const float4*)(x + (size_t)row * 128 + l0 + q * 4);
            }
            #pragma unroll
            for (int k = 0; k < 4; ++k) {
                float4 wt = ((const float4*)(WT + (q * 4 + k) * 132))[jc];
                #pragma unroll
                for (int ri = 0; ri < 4; ++ri) {
                    float xv = (k == 0) ? xq[ri].x : (k == 1) ? xq[ri].y
                             : (k == 2) ? xq[ri].z : xq[ri].w;
                    acc[ri][0] += xv * wt.x;
                    acc[ri][1] += xv * wt.y;
                    acc[ri][2] += xv * wt.z;
                    acc[ri][3] += xv * wt.w;
                }
            }
        }
    }

    #pragma unroll
    for (int ri = 0; ri < 4; ++ri) {
        float ss = acc[ri][0]*acc[ri][0] + acc[ri][1]*acc[ri][1]
                 + acc[ri][2]*acc[ri][2] + acc[ri][3]*acc[ri][3];
        ss += __shfl_xor(ss, 1);
        ss += __shfl_xor(ss, 2);
        ss += __shfl_xor(ss, 4);
        float inv = 1.0f / fmaxf(sqrtf(ss), 1e-12f);
        int row = row0 + rg * 4 + ri;
        if (row < n) {
            float4 o;
            o.x = acc[ri][0]*inv; o.y = acc[ri][1]*inv;
            o.z = acc[ri][2]*inv; o.w = acc[ri][3]*inv;
            ((float4*)(h + (size_t)row * 128))[jc] = o;
        }
    }
}

// ---------------------------------------------------------------------------
// Cooperative CSR build: prep -> hist -> 3-phase padded scan -> scatter,
// one kernel, grid.sync() between phases (verified phase code, r12-r16).
// 256 blocks x 256 threads: trivially co-resident.
// ---------------------------------------------------------------------------
__global__ __launch_bounds__(256)
void csr_build_kernel(const void* __restrict__ st, long long m, int n,
                      float* __restrict__ h, int* __restrict__ cnt,
                      int* __restrict__ row_ptr, int* __restrict__ cursor,
                      int* __restrict__ edge_src, long long padcap,
                      const int* __restrict__ raw, int* __restrict__ idx64,
                      int* __restrict__ bsum, int* __restrict__ boff,
                      int* __restrict__ total)
{
    cg::grid_group grid = cg::this_grid();
    const int  b   = blockIdx.x, t = threadIdx.x;
    const long long gid = (long long)b * 256 + t;
    const long long gsz = (long long)gridDim.x * 256;
    const int  chunk = (n + SCB - 1) / SCB;
    __shared__ int lds[256];

    // ---- phase A: zero cnt, zero dummy h row, fill padded edge_src, detect
    for (long long k = gid; k < padcap; k += gsz) {
        if (k < n) cnt[k] = 0;
        if (k < 128) h[(size_t)n * 128 + k] = 0.0f;
        edge_src[k] = n;
    }
    if (gid == 0) {
        int all_zero = 1;
        for (int k = 1; k < 64; k += 2)
            if (raw[k] != 0) { all_zero = 0; break; }
        *idx64 = all_zero;
    }
    grid.sync();

    // ---- phase B: histogram
    const int is64 = *idx64;
    for (long long e = gid; e < m; e += gsz) {
        int tg = load_idx(st, m + e, is64);
        if (tg >= 0 && tg < n) atomicAdd(&cnt[tg], 1);
    }
    grid.sync();

    // ---- phase C1: per-block padded partial sums
    {
        int lo = b * chunk, hi = min(lo + chunk, n);
        int s = 0;
        for (int i = lo + t; i < hi; i += 256) s += (cnt[i] + 3) & ~3;
        lds[t] = s; __syncthreads();
        for (int off = 128; off > 0; off >>= 1) {
            if (t < off) lds[t] += lds[t + off];
            __syncthreads();
        }
        if (t == 0) bsum[b] = lds[0];
    }
    grid.sync();

    // ---- phase C2: block 0 scans the 256 partials
    if (b == 0) {
        int v = bsum[t];
        lds[t] = v; __syncthreads();
        for (int off = 1; off < 256; off <<= 1) {
            int u = (t >= off) ? lds[t - off] : 0;
            __syncthreads();
            lds[t] += u;
            __syncthreads();
        }
        boff[t] = lds[t] - v;
        if (t == 255) *total = lds[255];
    }
    grid.sync();

    // ---- phase C3: per-block chunk scan, write row_ptr/cursor
    {
        int lo = b * chunk, hi = min(lo + chunk, n);
        int run = boff[b];
        for (int base = lo; base < hi; base += 256) {
            int i = base + t;
            int v = (i < hi) ? ((cnt[i] + 3) & ~3) : 0;
            lds[t] = v; __syncthreads();
            for (int off = 1; off < 256; off <<= 1) {
                int u = (t >= off) ? lds[t - off] : 0;
                __syncthreads();
                lds[t] += u;
                __syncthreads();
            }
            if (i < hi) {
                int excl = run + lds[t] - v;
                row_ptr[i] = excl;
                cursor[i]  = excl;
            }
            run += lds[255];
            __syncthreads();
        }
        if (b == 0 && t == 0) row_ptr[n] = *total;
    }
    grid.sync();

    // ---- phase D: scatter
    for (long long e = gid; e < m; e += gsz) {
        int tg = load_idx(st, m + e, is64);
        int sc = load_idx(st, e, is64);
        if (tg >= 0 && tg < n) {
            int pos = atomicAdd(&cursor[tg], 1);
            edge_src[pos] = sc;
        }
    }
}

// ---------------------------------------------------------------------------
// Routing v5: quartet layout on padded CSR (r16) + software-pipelined cached
// replay (prefetch j+1 from LDS before consuming j; arrays padded +1 slot).
// ---------------------------------------------------------------------------
__global__ __launch_bounds__(64 * WPB)
void route_kernel(const float* __restrict__ h, const int* __restrict__ row_ptr,
                  const int* __restrict__ edge_src, float* __restrict__ out, int n)
{
    __shared__ float4 zlsA[WPB][CAPQ + 1][64];
    __shared__ float4 zlsB[WPB][CAPQ + 1][64];

    int wv   = threadIdx.x >> 6;
    int wid  = __builtin_amdgcn_readfirstlane(blockIdx.x * WPB + wv);
    int lane = threadIdx.x & 63;
    int row  = lane >> 4;     // which edge of the quartet
    int rl   = lane & 15;     // lane within row: dims [rl*8, rl*8+8)
    if (wid >= n) return;

    const float4* __restrict__ h4 = (const float4*)h;
    float4 cA = h4[(size_t)wid * 32 + rl * 2];
    float4 cB = h4[(size_t)wid * 32 + rl * 2 + 1];

    const int e0  = row_ptr[wid];
    const int np  = (row_ptr[wid + 1] - e0) >> 2;   // padded quartet steps
    const int ncp = np < CAPQ ? np : CAPQ;
    const float selfm = (row == 0) ? 1.0f : 0.0f;

    float4 aA, aB;

    // ---- iteration 0: gather, cache (SoA), compute — branch-free loads ----
    aA.x = cA.x*selfm; aA.y = cA.y*selfm; aA.z = cA.z*selfm; aA.w = cA.w*selfm;
    aB.x = cB.x*selfm; aB.y = cB.y*selfm; aB.z = cB.z*selfm; aB.w = cB.w*selfm;
    for (int j = 0; j < np; ++j) {
        int s = edge_src[e0 + 4 * j + row];
        float4 zA = h4[(size_t)s * 32 + rl * 2];
        float4 zB = h4[(size_t)s * 32 + rl * 2 + 1];
        if (j < ncp) {
            zlsA[wv][j][lane] = zA;
            zlsB[wv][j][lane] = zB;
        }
        quad_acc(zA, zB, cA, cB, aA, aB);
    }
    {
        aA.x = sum_x32(sum_x16(aA.x)); aA.y = sum_x32(sum_x16(aA.y));
        aA.z = sum_x32(sum_x16(aA.z)); aA.w = sum_x32(sum_x16(aA.w));
        aB.x = sum_x32(sum_x16(aB.x)); aB.y = sum_x32(sum_x16(aB.y));
        aB.z = sum_x32(sum_x16(aB.z)); aB.w = sum_x32(sum_x16(aB.w));
        float ss = aA.x*aA.x + aA.y*aA.y + aA.z*aA.z + aA.w*aA.w
                 + aB.x*aB.x + aB.y*aB.y + aB.z*aB.z + aB.w*aB.w;
        ss = grpsum4(ss);
        float inv = __builtin_amdgcn_rcpf(fmaxf(sqrtf(ss), 1e-12f));
        cA.x = aA.x*inv; cA.y = aA.y*inv; cA.z = aA.z*inv; cA.w = aA.w*inv;
        cB.x = aB.x*inv; cB.y = aB.y*inv; cB.z = aB.z*inv; cB.w = aB.w*inv;
    }

    // ---- iterations 1..5: software-pipelined LDS replay (+ global tail) ----
    #pragma unroll 1
    for (int it = 1; it < ROUTIT; ++it) {
        aA.x = cA.x*selfm; aA.y = cA.y*selfm; aA.z = cA.z*selfm; aA.w = cA.w*selfm;
        aB.x = cB.x*selfm; aB.y = cB.y*selfm; aB.z = cB.z*selfm; aB.w = cB.w*selfm;
        float4 zA0 = zlsA[wv][0][lane];
        float4 zB0 = zlsB[wv][0][lane];
        #pragma unroll 2
        for (int j = 0; j < ncp; ++j) {
            float4 zA1 = zlsA[wv][j + 1][lane];   // pad slot makes this safe
            float4 zB1 = zlsB[wv][j + 1][lane];
            quad_acc(zA0, zB0, cA, cB, aA, aB);
            zA0 = zA1; zB0 = zB1;
        }
        for (int j = ncp; j < np; ++j) {
            int s = edge_src[e0 + 4 * j + row];
            float4 zA = h4[(size_t)s * 32 + rl * 2];
            float4 zB = h4[(size_t)s * 32 + rl * 2 + 1];
            quad_acc(zA, zB, cA, cB, aA, aB);
        }
        aA.x = sum_x32(sum_x16(aA.x)); aA.y = sum_x32(sum_x16(aA.y));
        aA.z = sum_x32(sum_x16(aA.z)); aA.w = sum_x32(sum_x16(aA.w));
        aB.x = sum_x32(sum_x16(aB.x)); aB.y = sum_x32(sum_x16(aB.y));
        aB.z = sum_x32(sum_x16(aB.z)); aB.w = sum_x32(sum_x16(aB.w));
        float ss = aA.x*aA.x + aA.y*aA.y + aA.z*aA.z + aA.w*aA.w
                 + aB.x*aB.x + aB.y*aB.y + aB.z*aB.z + aB.w*aB.w;
        ss = grpsum4(ss);
        float inv = __builtin_amdgcn_rcpf(fmaxf(sqrtf(ss), 1e-12f));
        cA.x = aA.x*inv; cA.y = aA.y*inv; cA.z = aA.z*inv; cA.w = aA.w*inv;
        cB.x = aB.x*inv; cB.y = aB.y*inv; cB.z = aB.z*inv; cB.w = aB.w*inv;
    }

    if (row == 0) {
        ((float4*)out)[(size_t)wid * 32 + rl * 2]     = cA;
        ((float4*)out)[(size_t)wid * 32 + rl * 2 + 1] = cB;
    }
}

// ---------------------------------------------------------------------------
extern "C" void kernel_launch(void* const* d_in, const int* in_sizes, int n_in,
                              void* d_out, int out_size, void* d_ws, size_t ws_size,
                              hipStream_t stream)
{
    const float* x       = (const float*)d_in[0];
    const void*  src_trg = d_in[1];
    const float* W       = (const float*)d_in[2];
    const float* b       = (const float*)d_in[3];
    float*       out     = (float*)d_out;

    int n = in_sizes[0] / 128;
    long long m = in_sizes[1] / 2;
    long long padcap = m + 3LL * n + 4;   // worst-case padded edge count

    // workspace layout (~61 MB)
    float* h        = (float*)d_ws;                      // (n+1)*128 floats
    int*   cnt      = (int*)(h + (size_t)(n + 1) * 128); // n
    int*   row_ptr  = cnt + n;                           // n+1
    int*   cursor   = row_ptr + (n + 1);                 // n
    int*   edge_src = cursor + n;                        // padcap ints
    int*   idx64    = edge_src + padcap;                 // 1 flag
    int*   bsum     = idx64 + 1;                         // SCB
    int*   boff     = bsum + SCB;                        // SCB
    int*   total    = boff + SCB;                        // 1
    const int* raw  = (const int*)src_trg;

    hipLaunchKernelGGL(gemm_norm_kernel, dim3((n + 31) / 32), dim3(256), 0, stream,
                       x, W, b, h, n);

    void* kargs[] = { (void*)&src_trg, (void*)&m, (void*)&n, (void*)&h,
                      (void*)&cnt, (void*)&row_ptr, (void*)&cursor,
                      (void*)&edge_src, (void*)&padcap, (void*)&raw,
                      (void*)&idx64, (void*)&bsum, (void*)&boff, (void*)&total };
    hipLaunchCooperativeKernel((void*)csr_build_kernel, dim3(SCB), dim3(256),
                               kargs, 0, stream);

    hipLaunchKernelGGL(route_kernel, dim3((n + WPB - 1) / WPB), dim3(64 * WPB), 0, stream,
                       h, row_ptr, edge_src, out, n);
}

// Round 18
// 593.984 us; speedup vs baseline: 1.2327x; 1.2327x over previous
//
#include <hip/hip_runtime.h>
#include <math.h>

#define ROUTIT 6
#define CAPQ 5   // cached quartet-steps per wave (+1 pad slot for prefetch)
#define WPB 2    // waves per block in route_kernel
#define SCB 256  // scan blocks

__device__ __forceinline__ int load_idx(const void* p, long long i, int is64)
{
    if (is64) return (int)((const long long*)p)[i];
    return ((const int*)p)[i];
}

// ---------------------------------------------------------------------------
// DPP helpers (VALU pipe) — verified r8-17.
// ---------------------------------------------------------------------------
template <int CTRL>
__device__ __forceinline__ float dpp_add(float x)
{
    int y = __builtin_amdgcn_update_dpp(0, __float_as_int(x), CTRL, 0xf, 0xf, true);
    return x + __int_as_float(y);
}

__device__ __forceinline__ float grpsum4(float p)
{
    p = dpp_add<0xB1>(p);   // quad_perm xor1
    p = dpp_add<0x4E>(p);   // quad_perm xor2
    return p;
}

__device__ __forceinline__ float rowtotal16(float x)
{
    x = dpp_add<0x124>(x);  // row_ror:4
    x = dpp_add<0x128>(x);  // row_ror:8
    return x;
}

__device__ __forceinline__ float sum_x16(float x)
{
#if __has_builtin(__builtin_amdgcn_permlane16_swap)
    unsigned u = __float_as_uint(x);
    auto r = __builtin_amdgcn_permlane16_swap(u, u, false, false);
    return __uint_as_float(r[0]) + __uint_as_float(r[1]);
#else
    return x + __shfl_xor(x, 16);
#endif
}

__device__ __forceinline__ float sum_x32(float x)
{
#if __has_builtin(__builtin_amdgcn_permlane32_swap)
    unsigned u = __float_as_uint(x);
    auto r = __builtin_amdgcn_permlane32_swap(u, u, false, false);
    return __uint_as_float(r[0]) + __uint_as_float(r[1]);
#else
    return x + __shfl_xor(x, 32);
#endif
}

// per-quartet-step (verified r15-17). Dummy edges (z=0) are inert.
__device__ __forceinline__ void quad_acc(const float4& zA, const float4& zB,
                                         const float4& cA, const float4& cB,
                                         float4& aA, float4& aB)
{
    float p = zA.x*cA.x + zA.y*cA.y + zA.z*cA.z + zA.w*cA.w
            + zB.x*cB.x + zB.y*cB.y + zB.z*cB.z + zB.w*cB.w;
    p = grpsum4(p);                     // 32-dim channel dot, |p| <= 1
    float ex = __expf(p);
    float d  = rowtotal16(ex);          // softmax denom (4 channels, in-row)
    float w  = ex * __builtin_amdgcn_rcpf(d);
    aA.x += w * zA.x;  aA.y += w * zA.y;  aA.z += w * zA.z;  aA.w += w * zA.w;
    aB.x += w * zB.x;  aB.y += w * zB.y;  aB.z += w * zB.z;  aB.w += w * zB.w;
}

// ---------------------------------------------------------------------------
// GEMM + per-channel L2 normalize (fp32 h) — round-13 v3 (kept).
// ---------------------------------------------------------------------------
__global__ __launch_bounds__(256)
void gemm_norm_kernel(const float* __restrict__ x, const float* __restrict__ W,
                      const float* __restrict__ b, float* __restrict__ h, int n)
{
    __shared__ float WT[32 * 132];    // WT[lc*132 + j] = W[j][l0+lc]

    const int tid  = threadIdx.x;
    const int jc   = tid & 31;
    const int rg   = tid >> 5;
    const int row0 = blockIdx.x * 32;

    float4 bb = ((const float4*)b)[jc];
    float acc[4][4];
    #pragma unroll
    for (int ri = 0; ri < 4; ++ri) {
        acc[ri][0] = bb.x; acc[ri][1] = bb.y; acc[ri][2] = bb.z; acc[ri][3] = bb.w;
    }

    for (int l0 = 0; l0 < 128; l0 += 32) {
        __syncthreads();
        for (int t = 0; t < 16; ++t) {
            int idx = t * 256 + tid;
            int j = idx >> 5, lc = idx & 31;
            WT[lc * 132 + j] = W[j * 128 + l0 + lc];
        }
        __syncthreads();

        #pragma unroll 2
        for (int q = 0; q < 8; ++q) {
            float4 xq[4];
            #pragma unroll
            for (int ri = 0; ri < 4; ++ri) {
                int row = row0 + rg * 4 + ri;
                row = row < n ? row : n - 1;
                xq[ri] = *(const float4*)(x + (size_t)row * 128 + l0 + q * 4);
            }
            #pragma unroll
            for (int k = 0; k < 4; ++k) {
                float4 wt = ((const float4*)(WT + (q * 4 + k) * 132))[jc];
                #pragma unroll
                for (int ri = 0; ri < 4; ++ri) {
                    float xv = (k == 0) ? xq[ri].x : (k == 1) ? xq[ri].y
                             : (k == 2) ? xq[ri].z : xq[ri].w;
                    acc[ri][0] += xv * wt.x;
                    acc[ri][1] += xv * wt.y;
                    acc[ri][2] += xv * wt.z;
                    acc[ri][3] += xv * wt.w;
                }
            }
        }
    }

    #pragma unroll
    for (int ri = 0; ri < 4; ++ri) {
        float ss = acc[ri][0]*acc[ri][0] + acc[ri][1]*acc[ri][1]
                 + acc[ri][2]*acc[ri][2] + acc[ri][3]*acc[ri][3];
        ss += __shfl_xor(ss, 1);
        ss += __shfl_xor(ss, 2);
        ss += __shfl_xor(ss, 4);
        float inv = 1.0f / fmaxf(sqrtf(ss), 1e-12f);
        int row = row0 + rg * 4 + ri;
        if (row < n) {
            float4 o;
            o.x = acc[ri][0]*inv; o.y = acc[ri][1]*inv;
            o.z = acc[ri][2]*inv; o.w = acc[ri][3]*inv;
            ((float4*)(h + (size_t)row * 128))[jc] = o;
        }
    }
}

// ---------------------------------------------------------------------------
// CSR build — SEPARATE kernels (r16 structure, verified). The r17 cooperative
// fusion capped hist/scatter at 1 block/CU (11.8% occ) and cost +280 us:
// memory-bound phases need large grids, not co-residency.
// ---------------------------------------------------------------------------
__global__ void prep_kernel(int* __restrict__ cnt, int n,
                            float* __restrict__ h,
                            int* __restrict__ edge_src, long long padcap,
                            const int* __restrict__ raw, int* __restrict__ flag)
{
    long long i = (long long)blockIdx.x * blockDim.x + threadIdx.x;
    long long stride = (long long)gridDim.x * blockDim.x;
    for (long long k = i; k < padcap; k += stride) {
        if (k < n) cnt[k] = 0;
        if (k < 128) h[(size_t)n * 128 + k] = 0.0f;
        edge_src[k] = n;
    }
    if (i == 0) {
        int all_zero = 1;
        for (int k = 1; k < 64; k += 2)
            if (raw[k] != 0) { all_zero = 0; break; }
        *flag = all_zero;
    }
}

__global__ void hist_kernel(const void* __restrict__ st, long long m, int n,
                            const int* __restrict__ idx64, int* __restrict__ cnt)
{
    long long e = (long long)blockIdx.x * blockDim.x + threadIdx.x;
    if (e < m) {
        int t = load_idx(st, m + e, *idx64);
        if (t >= 0 && t < n) atomicAdd(&cnt[t], 1);
    }
}

__global__ __launch_bounds__(256)
void scan_partial_kernel(const int* __restrict__ cnt, int n, int chunk,
                         int* __restrict__ bsum)
{
    int b = blockIdx.x, t = threadIdx.x;
    int lo = b * chunk, hi = min(lo + chunk, n);
    int s = 0;
    for (int i = lo + t; i < hi; i += 256) s += (cnt[i] + 3) & ~3;
    __shared__ int red[256];
    red[t] = s; __syncthreads();
    for (int off = 128; off > 0; off >>= 1) {
        if (t < off) red[t] += red[t + off];
        __syncthreads();
    }
    if (t == 0) bsum[b] = red[0];
}

__global__ __launch_bounds__(256)
void scan_offsets_kernel(const int* __restrict__ bsum, int nb,
                         int* __restrict__ boff, int* __restrict__ total)
{
    __shared__ int lds[256];
    int t = threadIdx.x;
    int v = (t < nb) ? bsum[t] : 0;
    lds[t] = v; __syncthreads();
    for (int off = 1; off < 256; off <<= 1) {
        int u = (t >= off) ? lds[t - off] : 0;
        __syncthreads();
        lds[t] += u;
        __syncthreads();
    }
    if (t < nb) boff[t] = lds[t] - v;
    if (t == 255) *total = lds[255];
}

__global__ __launch_bounds__(256)
void scan_write_kernel(const int* __restrict__ cnt, int n, int chunk,
                       const int* __restrict__ boff, const int* __restrict__ total,
                       int* __restrict__ row_ptr, int* __restrict__ cursor)
{
    int b = blockIdx.x, t = threadIdx.x;
    int lo = b * chunk, hi = min(lo + chunk, n);
    __shared__ int lds[256];
    int run = boff[b];
    for (int base = lo; base < hi; base += 256) {
        int i = base + t;
        int v = (i < hi) ? ((cnt[i] + 3) & ~3) : 0;
        lds[t] = v; __syncthreads();
        for (int off = 1; off < 256; off <<= 1) {
            int u = (t >= off) ? lds[t - off] : 0;
            __syncthreads();
            lds[t] += u;
            __syncthreads();
        }
        if (i < hi) {
            int excl = run + lds[t] - v;
            row_ptr[i] = excl;
            cursor[i]  = excl;
        }
        run += lds[255];
        __syncthreads();
    }
    if (b == 0 && t == 0) row_ptr[n] = *total;
}

__global__ void scatter_kernel(const void* __restrict__ st, long long m, int n,
                               const int* __restrict__ idx64,
                               int* __restrict__ cursor, int* __restrict__ edge_src)
{
    long long e = (long long)blockIdx.x * blockDim.x + threadIdx.x;
    if (e < m) {
        int is64 = *idx64;
        int t = load_idx(st, m + e, is64);
        int s = load_idx(st, e, is64);
        if (t >= 0 && t < n) {
            int pos = atomicAdd(&cursor[t], 1);
            edge_src[pos] = s;
        }
    }
}

// ---------------------------------------------------------------------------
// Routing v5 (r17, kept): quartet layout on padded CSR + software-pipelined
// cached replay (prefetch j+1 from LDS before consuming j; +1 pad slot).
// ---------------------------------------------------------------------------
__global__ __launch_bounds__(64 * WPB)
void route_kernel(const float* __restrict__ h, const int* __restrict__ row_ptr,
                  const int* __restrict__ edge_src, float* __restrict__ out, int n)
{
    __shared__ float4 zlsA[WPB][CAPQ + 1][64];
    __shared__ float4 zlsB[WPB][CAPQ + 1][64];

    int wv   = threadIdx.x >> 6;
    int wid  = __builtin_amdgcn_readfirstlane(blockIdx.x * WPB + wv);
    int lane = threadIdx.x & 63;
    int row  = lane >> 4;     // which edge of the quartet
    int rl   = lane & 15;     // lane within row: dims [rl*8, rl*8+8)
    if (wid >= n) return;

    const float4* __restrict__ h4 = (const float4*)h;
    float4 cA = h4[(size_t)wid * 32 + rl * 2];
    float4 cB = h4[(size_t)wid * 32 + rl * 2 + 1];

    const int e0  = row_ptr[wid];
    const int np  = (row_ptr[wid + 1] - e0) >> 2;   // padded quartet steps
    const int ncp = np < CAPQ ? np : CAPQ;
    const float selfm = (row == 0) ? 1.0f : 0.0f;

    float4 aA, aB;

    // ---- iteration 0: gather, cache (SoA), compute — branch-free loads ----
    aA.x = cA.x*selfm; aA.y = cA.y*selfm; aA.z = cA.z*selfm; aA.w = cA.w*selfm;
    aB.x = cB.x*selfm; aB.y = cB.y*selfm; aB.z = cB.z*selfm; aB.w = cB.w*selfm;
    for (int j = 0; j < np; ++j) {
        int s = edge_src[e0 + 4 * j + row];
        float4 zA = h4[(size_t)s * 32 + rl * 2];
        float4 zB = h4[(size_t)s * 32 + rl * 2 + 1];
        if (j < ncp) {
            zlsA[wv][j][lane] = zA;
            zlsB[wv][j][lane] = zB;
        }
        quad_acc(zA, zB, cA, cB, aA, aB);
    }
    {
        aA.x = sum_x32(sum_x16(aA.x)); aA.y = sum_x32(sum_x16(aA.y));
        aA.z = sum_x32(sum_x16(aA.z)); aA.w = sum_x32(sum_x16(aA.w));
        aB.x = sum_x32(sum_x16(aB.x)); aB.y = sum_x32(sum_x16(aB.y));
        aB.z = sum_x32(sum_x16(aB.z)); aB.w = sum_x32(sum_x16(aB.w));
        float ss = aA.x*aA.x + aA.y*aA.y + aA.z*aA.z + aA.w*aA.w
                 + aB.x*aB.x + aB.y*aB.y + aB.z*aB.z + aB.w*aB.w;
        ss = grpsum4(ss);
        float inv = __builtin_amdgcn_rcpf(fmaxf(sqrtf(ss), 1e-12f));
        cA.x = aA.x*inv; cA.y = aA.y*inv; cA.z = aA.z*inv; cA.w = aA.w*inv;
        cB.x = aB.x*inv; cB.y = aB.y*inv; cB.z = aB.z*inv; cB.w = aB.w*inv;
    }

    // ---- iterations 1..5: software-pipelined LDS replay (+ global tail) ----
    #pragma unroll 1
    for (int it = 1; it < ROUTIT; ++it) {
        aA.x = cA.x*selfm; aA.y = cA.y*selfm; aA.z = cA.z*selfm; aA.w = cA.w*selfm;
        aB.x = cB.x*selfm; aB.y = cB.y*selfm; aB.z = cB.z*selfm; aB.w = cB.w*selfm;
        float4 zA0 = zlsA[wv][0][lane];
        float4 zB0 = zlsB[wv][0][lane];
        #pragma unroll 2
        for (int j = 0; j < ncp; ++j) {
            float4 zA1 = zlsA[wv][j + 1][lane];   // pad slot makes this safe
            float4 zB1 = zlsB[wv][j + 1][lane];
            quad_acc(zA0, zB0, cA, cB, aA, aB);
            zA0 = zA1; zB0 = zB1;
        }
        for (int j = ncp; j < np; ++j) {
            int s = edge_src[e0 + 4 * j + row];
            float4 zA = h4[(size_t)s * 32 + rl * 2];
            float4 zB = h4[(size_t)s * 32 + rl * 2 + 1];
            quad_acc(zA, zB, cA, cB, aA, aB);
        }
        aA.x = sum_x32(sum_x16(aA.x)); aA.y = sum_x32(sum_x16(aA.y));
        aA.z = sum_x32(sum_x16(aA.z)); aA.w = sum_x32(sum_x16(aA.w));
        aB.x = sum_x32(sum_x16(aB.x)); aB.y = sum_x32(sum_x16(aB.y));
        aB.z = sum_x32(sum_x16(aB.z)); aB.w = sum_x32(sum_x16(aB.w));
        float ss = aA.x*aA.x + aA.y*aA.y + aA.z*aA.z + aA.w*aA.w
                 + aB.x*aB.x + aB.y*aB.y + aB.z*aB.z + aB.w*aB.w;
        ss = grpsum4(ss);
        float inv = __builtin_amdgcn_rcpf(fmaxf(sqrtf(ss), 1e-12f));
        cA.x = aA.x*inv; cA.y = aA.y*inv; cA.z = aA.z*inv; cA.w = aA.w*inv;
        cB.x = aB.x*inv; cB.y = aB.y*inv; cB.z = aB.z*inv; cB.w = aB.w*inv;
    }

    if (row == 0) {
        ((float4*)out)[(size_t)wid * 32 + rl * 2]     = cA;
        ((float4*)out)[(size_t)wid * 32 + rl * 2 + 1] = cB;
    }
}

// ---------------------------------------------------------------------------
extern "C" void kernel_launch(void* const* d_in, const int* in_sizes, int n_in,
                              void* d_out, int out_size, void* d_ws, size_t ws_size,
                              hipStream_t stream)
{
    const float* x       = (const float*)d_in[0];
    const void*  src_trg = d_in[1];
    const float* W       = (const float*)d_in[2];
    const float* b       = (const float*)d_in[3];
    float*       out     = (float*)d_out;

    int n = in_sizes[0] / 128;
    long long m = in_sizes[1] / 2;
    int chunk = (n + SCB - 1) / SCB;
    long long padcap = m + 3LL * n + 4;   // worst-case padded edge count

    // workspace layout (~61 MB)
    float* h        = (float*)d_ws;                      // (n+1)*128 floats
    int*   cnt      = (int*)(h + (size_t)(n + 1) * 128); // n
    int*   row_ptr  = cnt + n;                           // n+1
    int*   cursor   = row_ptr + (n + 1);                 // n
    int*   edge_src = cursor + n;                        // padcap ints
    int*   idx64    = edge_src + padcap;                 // 1 flag
    int*   bsum     = idx64 + 1;                         // SCB
    int*   boff     = bsum + SCB;                        // SCB
    int*   total    = boff + SCB;                        // 1

    hipLaunchKernelGGL(gemm_norm_kernel, dim3((n + 31) / 32), dim3(256), 0, stream,
                       x, W, b, h, n);
    hipLaunchKernelGGL(prep_kernel, dim3(2048), dim3(256), 0, stream,
                       cnt, n, h, edge_src, padcap, (const int*)src_trg, idx64);
    hipLaunchKernelGGL(hist_kernel, dim3((int)((m + 255) / 256)), dim3(256), 0, stream,
                       src_trg, m, n, idx64, cnt);
    hipLaunchKernelGGL(scan_partial_kernel, dim3(SCB), dim3(256), 0, stream,
                       cnt, n, chunk, bsum);
    hipLaunchKernelGGL(scan_offsets_kernel, dim3(1), dim3(256), 0, stream,
                       bsum, SCB, boff, total);
    hipLaunchKernelGGL(scan_write_kernel, dim3(SCB), dim3(256), 0, stream,
                       cnt, n, chunk, boff, total, row_ptr, cursor);
    hipLaunchKernelGGL(scatter_kernel, dim3((int)((m + 255) / 256)), dim3(256), 0, stream,
                       src_trg, m, n, idx64, cursor, edge_src);
    hipLaunchKernelGGL(route_kernel, dim3((n + WPB - 1) / WPB), dim3(64 * WPB), 0, stream,
                       h, row_ptr, edge_src, out, n);
}

// Round 19
// 541.107 us; speedup vs baseline: 1.3532x; 1.0977x over previous
//
#include <hip/hip_runtime.h>
#include <math.h>

#define ROUTIT 6
#define CAPQ 5   // cached quartet-steps per wave; 2 waves * 5 * 2KB = 20 KB/block
#define WPB 2    // waves per block in route_kernel
#define SCB 256  // scan blocks

__device__ __forceinline__ int load_idx(const void* p, long long i, int is64)
{
    if (is64) return (int)((const long long*)p)[i];
    return ((const int*)p)[i];
}

// ---------------------------------------------------------------------------
// DPP helpers (VALU pipe) — verified r8-18.
// ---------------------------------------------------------------------------
template <int CTRL>
__device__ __forceinline__ float dpp_add(float x)
{
    int y = __builtin_amdgcn_update_dpp(0, __float_as_int(x), CTRL, 0xf, 0xf, true);
    return x + __int_as_float(y);
}

// sum over a 4-lane group (one channel's 32 dims at 8 dims/lane)
__device__ __forceinline__ float grpsum4(float p)
{
    p = dpp_add<0xB1>(p);   // quad_perm xor1
    p = dpp_add<0x4E>(p);   // quad_perm xor2
    return p;
}

// sum of the four 4-lane-group values within a 16-row (input group-constant)
__device__ __forceinline__ float rowtotal16(float x)
{
    x = dpp_add<0x124>(x);  // row_ror:4
    x = dpp_add<0x128>(x);  // row_ror:8
    return x;
}

// x[l] + x[l^16] / x[l] + x[l^32] — permlane swap builtins (verified r15/16)
__device__ __forceinline__ float sum_x16(float x)
{
#if __has_builtin(__builtin_amdgcn_permlane16_swap)
    unsigned u = __float_as_uint(x);
    auto r = __builtin_amdgcn_permlane16_swap(u, u, false, false);
    return __uint_as_float(r[0]) + __uint_as_float(r[1]);
#else
    return x + __shfl_xor(x, 16);
#endif
}

__device__ __forceinline__ float sum_x32(float x)
{
#if __has_builtin(__builtin_amdgcn_permlane32_swap)
    unsigned u = __float_as_uint(x);
    auto r = __builtin_amdgcn_permlane32_swap(u, u, false, false);
    return __uint_as_float(r[0]) + __uint_as_float(r[1]);
#else
    return x + __shfl_xor(x, 32);
#endif
}

// per-quartet-step: this lane's edge is its 16-row; z,c = 8 dims (2 float4).
// Dummy edges (z = 0) are inert: p=0 -> ex=1 enters only this row's own
// denominator; w*z = 0.
__device__ __forceinline__ void quad_acc(const float4& zA, const float4& zB,
                                         const float4& cA, const float4& cB,
                                         float4& aA, float4& aB)
{
    float p = zA.x*cA.x + zA.y*cA.y + zA.z*cA.z + zA.w*cA.w
            + zB.x*cB.x + zB.y*cB.y + zB.z*cB.z + zB.w*cB.w;
    p = grpsum4(p);                     // 32-dim channel dot, |p| <= 1
    float ex = __expf(p);
    float d  = rowtotal16(ex);          // softmax denom (4 channels, in-row)
    float w  = ex * __builtin_amdgcn_rcpf(d);
    aA.x += w * zA.x;  aA.y += w * zA.y;  aA.z += w * zA.z;  aA.w += w * zA.w;
    aB.x += w * zB.x;  aB.y += w * zB.y;  aB.z += w * zB.z;  aB.w += w * zB.w;
}

// ---------------------------------------------------------------------------
// GEMM + per-channel L2 normalize (fp32 h) — round-13 v3 (kept).
// ---------------------------------------------------------------------------
__global__ __launch_bounds__(256)
void gemm_norm_kernel(const float* __restrict__ x, const float* __restrict__ W,
                      const float* __restrict__ b, float* __restrict__ h, int n)
{
    __shared__ float WT[32 * 132];    // WT[lc*132 + j] = W[j][l0+lc]

    const int tid  = threadIdx.x;
    const int jc   = tid & 31;
    const int rg   = tid >> 5;
    const int row0 = blockIdx.x * 32;

    float4 bb = ((const float4*)b)[jc];
    float acc[4][4];
    #pragma unroll
    for (int ri = 0; ri < 4; ++ri) {
        acc[ri][0] = bb.x; acc[ri][1] = bb.y; acc[ri][2] = bb.z; acc[ri][3] = bb.w;
    }

    for (int l0 = 0; l0 < 128; l0 += 32) {
        __syncthreads();
        for (int t = 0; t < 16; ++t) {
            int idx = t * 256 + tid;
            int j = idx >> 5, lc = idx & 31;
            WT[lc * 132 + j] = W[j * 128 + l0 + lc];
        }
        __syncthreads();

        #pragma unroll 2
        for (int q = 0; q < 8; ++q) {
            float4 xq[4];
            #pragma unroll
            for (int ri = 0; ri < 4; ++ri) {
                int row = row0 + rg * 4 + ri;
                row = row < n ? row : n - 1;
                xq[ri] = *(const float4*)(x + (size_t)row * 128 + l0 + q * 4);
            }
            #pragma unroll
            for (int k = 0; k < 4; ++k) {
                float4 wt = ((const float4*)(WT + (q * 4 + k) * 132))[jc];
                #pragma unroll
                for (int ri = 0; ri < 4; ++ri) {
                    float xv = (k == 0) ? xq[ri].x : (k == 1) ? xq[ri].y
                             : (k == 2) ? xq[ri].z : xq[ri].w;
                    acc[ri][0] += xv * wt.x;
                    acc[ri][1] += xv * wt.y;
                    acc[ri][2] += xv * wt.z;
                    acc[ri][3] += xv * wt.w;
                }
            }
        }
    }

    #pragma unroll
    for (int ri = 0; ri < 4; ++ri) {
        float ss = acc[ri][0]*acc[ri][0] + acc[ri][1]*acc[ri][1]
                 + acc[ri][2]*acc[ri][2] + acc[ri][3]*acc[ri][3];
        ss += __shfl_xor(ss, 1);
        ss += __shfl_xor(ss, 2);
        ss += __shfl_xor(ss, 4);
        float inv = 1.0f / fmaxf(sqrtf(ss), 1e-12f);
        int row = row0 + rg * 4 + ri;
        if (row < n) {
            float4 o;
            o.x = acc[ri][0]*inv; o.y = acc[ri][1]*inv;
            o.z = acc[ri][2]*inv; o.w = acc[ri][3]*inv;
            ((float4*)(h + (size_t)row * 128))[jc] = o;
        }
    }
}

// ---------------------------------------------------------------------------
// prep: zero cnt, zero h row n (the dummy row), pre-fill padded edge_src
// with n, detect idx dtype. All independent; grid-stride over padcap.
// ---------------------------------------------------------------------------
__global__ void prep_kernel(int* __restrict__ cnt, int n,
                            float* __restrict__ h,
                            int* __restrict__ edge_src, long long padcap,
                            const int* __restrict__ raw, int* __restrict__ flag)
{
    long long i = (long long)blockIdx.x * blockDim.x + threadIdx.x;
    long long stride = (long long)gridDim.x * blockDim.x;
    for (long long k = i; k < padcap; k += stride) {
        if (k < n) cnt[k] = 0;
        if (k < 128) h[(size_t)n * 128 + k] = 0.0f;
        edge_src[k] = n;
    }
    if (i == 0) {
        int all_zero = 1;
        for (int k = 1; k < 64; k += 2)
            if (raw[k] != 0) { all_zero = 0; break; }
        *flag = all_zero;
    }
}

__global__ void hist_kernel(const void* __restrict__ st, long long m, int n,
                            const int* __restrict__ idx64, int* __restrict__ cnt)
{
    long long e = (long long)blockIdx.x * blockDim.x + threadIdx.x;
    if (e < m) {
        int t = load_idx(st, m + e, *idx64);
        if (t >= 0 && t < n) atomicAdd(&cnt[t], 1);
    }
}

// ---- 3-phase parallel scan over PADDED degrees (pad4) ----
__global__ __launch_bounds__(256)
void scan_partial_kernel(const int* __restrict__ cnt, int n, int chunk,
                         int* __restrict__ bsum)
{
    int b = blockIdx.x, t = threadIdx.x;
    int lo = b * chunk, hi = min(lo + chunk, n);
    int s = 0;
    for (int i = lo + t; i < hi; i += 256) s += (cnt[i] + 3) & ~3;
    __shared__ int red[256];
    red[t] = s; __syncthreads();
    for (int off = 128; off > 0; off >>= 1) {
        if (t < off) red[t] += red[t + off];
        __syncthreads();
    }
    if (t == 0) bsum[b] = red[0];
}

__global__ __launch_bounds__(256)
void scan_offsets_kernel(const int* __restrict__ bsum, int nb,
                         int* __restrict__ boff, int* __restrict__ total)
{
    __shared__ int lds[256];
    int t = threadIdx.x;
    int v = (t < nb) ? bsum[t] : 0;
    lds[t] = v; __syncthreads();
    for (int off = 1; off < 256; off <<= 1) {
        int u = (t >= off) ? lds[t - off] : 0;
        __syncthreads();
        lds[t] += u;
        __syncthreads();
    }
    if (t < nb) boff[t] = lds[t] - v;
    if (t == 255) *total = lds[255];
}

__global__ __launch_bounds__(256)
void scan_write_kernel(const int* __restrict__ cnt, int n, int chunk,
                       const int* __restrict__ boff, const int* __restrict__ total,
                       int* __restrict__ row_ptr, int* __restrict__ cursor)
{
    int b = blockIdx.x, t = threadIdx.x;
    int lo = b * chunk, hi = min(lo + chunk, n);
    __shared__ int lds[256];
    int run = boff[b];
    for (int base = lo; base < hi; base += 256) {
        int i = base + t;
        int v = (i < hi) ? ((cnt[i] + 3) & ~3) : 0;
        lds[t] = v; __syncthreads();
        for (int off = 1; off < 256; off <<= 1) {
            int u = (t >= off) ? lds[t - off] : 0;
            __syncthreads();
            lds[t] += u;
            __syncthreads();
        }
        if (i < hi) {
            int excl = run + lds[t] - v;
            row_ptr[i] = excl;
            cursor[i]  = excl;
        }
        run += lds[255];
        __syncthreads();
    }
    if (b == 0 && t == 0) row_ptr[n] = *total;
}

__global__ void scatter_kernel(const void* __restrict__ st, long long m, int n,
                               const int* __restrict__ idx64,
                               int* __restrict__ cursor, int* __restrict__ edge_src)
{
    long long e = (long long)blockIdx.x * blockDim.x + threadIdx.x;
    if (e < m) {
        int is64 = *idx64;
        int t = load_idx(st, m + e, is64);
        int s = load_idx(st, e, is64);
        if (t >= 0 && t < n) {
            int pos = atomicAdd(&cursor[t], 1);
            edge_src[pos] = s;
        }
    }
}

// ---------------------------------------------------------------------------
// Routing v4 (r16, the verified best: 284 us): quartet layout (4 edges/step,
// 8 dims/lane) on a PADDED CSR — branch-free inner loop (dummy edges point
// at the zero row n and contribute nothing). No manual prefetch pipeline:
// r17/18 showed it costs occupancy (VGPR 68, occ 29.6%) for zero gain.
// ---------------------------------------------------------------------------
__global__ __launch_bounds__(64 * WPB)
void route_kernel(const float* __restrict__ h, const int* __restrict__ row_ptr,
                  const int* __restrict__ edge_src, float* __restrict__ out, int n)
{
    __shared__ float4 zlsA[WPB][CAPQ][64];
    __shared__ float4 zlsB[WPB][CAPQ][64];

    int wv   = threadIdx.x >> 6;
    int wid  = __builtin_amdgcn_readfirstlane(blockIdx.x * WPB + wv);
    int lane = threadIdx.x & 63;
    int row  = lane >> 4;     // which edge of the quartet
    int rl   = lane & 15;     // lane within row: dims [rl*8, rl*8+8)
    if (wid >= n) return;

    const float4* __restrict__ h4 = (const float4*)h;
    float4 cA = h4[(size_t)wid * 32 + rl * 2];
    float4 cB = h4[(size_t)wid * 32 + rl * 2 + 1];

    const int e0  = row_ptr[wid];
    const int np  = (row_ptr[wid + 1] - e0) >> 2;   // padded quartet steps
    const int ncp = np < CAPQ ? np : CAPQ;
    const float selfm = (row == 0) ? 1.0f : 0.0f;

    float4 aA, aB;

    // ---- iteration 0: gather, cache (SoA), compute — branch-free loads ----
    aA.x = cA.x*selfm; aA.y = cA.y*selfm; aA.z = cA.z*selfm; aA.w = cA.w*selfm;
    aB.x = cB.x*selfm; aB.y = cB.y*selfm; aB.z = cB.z*selfm; aB.w = cB.w*selfm;
    for (int j = 0; j < np; ++j) {
        int s = edge_src[e0 + 4 * j + row];
        float4 zA = h4[(size_t)s * 32 + rl * 2];
        float4 zB = h4[(size_t)s * 32 + rl * 2 + 1];
        if (j < ncp) {
            zlsA[wv][j][lane] = zA;
            zlsB[wv][j][lane] = zB;
        }
        quad_acc(zA, zB, cA, cB, aA, aB);
    }
    {
        aA.x = sum_x32(sum_x16(aA.x)); aA.y = sum_x32(sum_x16(aA.y));
        aA.z = sum_x32(sum_x16(aA.z)); aA.w = sum_x32(sum_x16(aA.w));
        aB.x = sum_x32(sum_x16(aB.x)); aB.y = sum_x32(sum_x16(aB.y));
        aB.z = sum_x32(sum_x16(aB.z)); aB.w = sum_x32(sum_x16(aB.w));
        float ss = aA.x*aA.x + aA.y*aA.y + aA.z*aA.z + aA.w*aA.w
                 + aB.x*aB.x + aB.y*aB.y + aB.z*aB.z + aB.w*aB.w;
        ss = grpsum4(ss);
        float inv = __builtin_amdgcn_rcpf(fmaxf(sqrtf(ss), 1e-12f));
        cA.x = aA.x*inv; cA.y = aA.y*inv; cA.z = aA.z*inv; cA.w = aA.w*inv;
        cB.x = aB.x*inv; cB.y = aB.y*inv; cB.z = aB.z*inv; cB.w = aB.w*inv;
    }

    // ---- iterations 1..5: replay cached steps from LDS (+ global tail) ----
    #pragma unroll 1
    for (int it = 1; it < ROUTIT; ++it) {
        aA.x = cA.x*selfm; aA.y = cA.y*selfm; aA.z = cA.z*selfm; aA.w = cA.w*selfm;
        aB.x = cB.x*selfm; aB.y = cB.y*selfm; aB.z = cB.z*selfm; aB.w = cB.w*selfm;
        #pragma unroll 2
        for (int j = 0; j < ncp; ++j) {
            float4 zA = zlsA[wv][j][lane];
            float4 zB = zlsB[wv][j][lane];
            quad_acc(zA, zB, cA, cB, aA, aB);
        }
        for (int j = ncp; j < np; ++j) {
            int s = edge_src[e0 + 4 * j + row];
            float4 zA = h4[(size_t)s * 32 + rl * 2];
            float4 zB = h4[(size_t)s * 32 + rl * 2 + 1];
            quad_acc(zA, zB, cA, cB, aA, aB);
        }
        aA.x = sum_x32(sum_x16(aA.x)); aA.y = sum_x32(sum_x16(aA.y));
        aA.z = sum_x32(sum_x16(aA.z)); aA.w = sum_x32(sum_x16(aA.w));
        aB.x = sum_x32(sum_x16(aB.x)); aB.y = sum_x32(sum_x16(aB.y));
        aB.z = sum_x32(sum_x16(aB.z)); aB.w = sum_x32(sum_x16(aB.w));
        float ss = aA.x*aA.x + aA.y*aA.y + aA.z*aA.z + aA.w*aA.w
                 + aB.x*aB.x + aB.y*aB.y + aB.z*aB.z + aB.w*aB.w;
        ss = grpsum4(ss);
        float inv = __builtin_amdgcn_rcpf(fmaxf(sqrtf(ss), 1e-12f));
        cA.x = aA.x*inv; cA.y = aA.y*inv; cA.z = aA.z*inv; cA.w = aA.w*inv;
        cB.x = aB.x*inv; cB.y = aB.y*inv; cB.z = aB.z*inv; cB.w = aB.w*inv;
    }

    if (row == 0) {
        ((float4*)out)[(size_t)wid * 32 + rl * 2]     = cA;
        ((float4*)out)[(size_t)wid * 32 + rl * 2 + 1] = cB;
    }
}

// ---------------------------------------------------------------------------
extern "C" void kernel_launch(void* const* d_in, const int* in_sizes, int n_in,
                              void* d_out, int out_size, void* d_ws, size_t ws_size,
                              hipStream_t stream)
{
    const float* x       = (const float*)d_in[0];
    const void*  src_trg = d_in[1];
    const float* W       = (const float*)d_in[2];
    const float* b       = (const float*)d_in[3];
    float*       out     = (float*)d_out;

    int n = in_sizes[0] / 128;
    long long m = in_sizes[1] / 2;
    int chunk = (n + SCB - 1) / SCB;
    long long padcap = m + 3LL * n + 4;   // worst-case padded edge count

    // workspace layout (~61 MB)
    float* h        = (float*)d_ws;                      // (n+1)*128 floats
    int*   cnt      = (int*)(h + (size_t)(n + 1) * 128); // n
    int*   row_ptr  = cnt + n;                           // n+1
    int*   cursor   = row_ptr + (n + 1);                 // n
    int*   edge_src = cursor + n;                        // padcap ints
    int*   idx64    = edge_src + padcap;                 // 1 flag
    int*   bsum     = idx64 + 1;                         // SCB
    int*   boff     = bsum + SCB;                        // SCB
    int*   total    = boff + SCB;                        // 1

    hipLaunchKernelGGL(gemm_norm_kernel, dim3((n + 31) / 32), dim3(256), 0, stream,
                       x, W, b, h, n);
    hipLaunchKernelGGL(prep_kernel, dim3(2048), dim3(256), 0, stream,
                       cnt, n, h, edge_src, padcap, (const int*)src_trg, idx64);
    hipLaunchKernelGGL(hist_kernel, dim3((int)((m + 255) / 256)), dim3(256), 0, stream,
                       src_trg, m, n, idx64, cnt);
    hipLaunchKernelGGL(scan_partial_kernel, dim3(SCB), dim3(256), 0, stream,
                       cnt, n, chunk, bsum);
    hipLaunchKernelGGL(scan_offsets_kernel, dim3(1), dim3(256), 0, stream,
                       bsum, SCB, boff, total);
    hipLaunchKernelGGL(scan_write_kernel, dim3(SCB), dim3(256), 0, stream,
                       cnt, n, chunk, boff, total, row_ptr, cursor);
    hipLaunchKernelGGL(scatter_kernel, dim3((int)((m + 255) / 256)), dim3(256), 0, stream,
                       src_trg, m, n, idx64, cursor, edge_src);
    hipLaunchKernelGGL(route_kernel, dim3((n + WPB - 1) / WPB), dim3(64 * WPB), 0, stream,
                       h, row_ptr, edge_src, out, n);
}

// Round 20
// 488.184 us; speedup vs baseline: 1.4999x; 1.1084x over previous
//
#include <hip/hip_runtime.h>
#include <math.h>

#define ROUTIT 6
#define CAPQ 5   // cached quartet-steps per wave; 2 waves * 5 * 2KB = 20 KB/block
#define WPB 2    // waves per block in route_kernel
#define SCB 256  // scan blocks

typedef _Float16 half8 __attribute__((ext_vector_type(8)));
typedef float    f32x4 __attribute__((ext_vector_type(4)));

__device__ __forceinline__ int load_idx(const void* p, long long i, int is64)
{
    if (is64) return (int)((const long long*)p)[i];
    return ((const int*)p)[i];
}

// ---------------------------------------------------------------------------
// DPP helpers (VALU pipe) — verified r8-19.
// ---------------------------------------------------------------------------
template <int CTRL>
__device__ __forceinline__ float dpp_add(float x)
{
    int y = __builtin_amdgcn_update_dpp(0, __float_as_int(x), CTRL, 0xf, 0xf, true);
    return x + __int_as_float(y);
}

__device__ __forceinline__ float grpsum4(float p)
{
    p = dpp_add<0xB1>(p);   // quad_perm xor1
    p = dpp_add<0x4E>(p);   // quad_perm xor2
    return p;
}

__device__ __forceinline__ float rowtotal16(float x)
{
    x = dpp_add<0x124>(x);  // row_ror:4
    x = dpp_add<0x128>(x);  // row_ror:8
    return x;
}

// full 16-lane row sum (xor1, xor2, ror4, ror8) — verified r8+
__device__ __forceinline__ float rowsum16(float p)
{
    p = dpp_add<0xB1>(p);
    p = dpp_add<0x4E>(p);
    p = dpp_add<0x124>(p);
    p = dpp_add<0x128>(p);
    return p;
}

__device__ __forceinline__ float sum_x16(float x)
{
#if __has_builtin(__builtin_amdgcn_permlane16_swap)
    unsigned u = __float_as_uint(x);
    auto r = __builtin_amdgcn_permlane16_swap(u, u, false, false);
    return __uint_as_float(r[0]) + __uint_as_float(r[1]);
#else
    return x + __shfl_xor(x, 16);
#endif
}

__device__ __forceinline__ float sum_x32(float x)
{
#if __has_builtin(__builtin_amdgcn_permlane32_swap)
    unsigned u = __float_as_uint(x);
    auto r = __builtin_amdgcn_permlane32_swap(u, u, false, false);
    return __uint_as_float(r[0]) + __uint_as_float(r[1]);
#else
    return x + __shfl_xor(x, 32);
#endif
}

// per-quartet-step (verified r15-19). Dummy edges (z = 0) are inert.
__device__ __forceinline__ void quad_acc(const float4& zA, const float4& zB,
                                         const float4& cA, const float4& cB,
                                         float4& aA, float4& aB)
{
    float p = zA.x*cA.x + zA.y*cA.y + zA.z*cA.z + zA.w*cA.w
            + zB.x*cB.x + zB.y*cB.y + zB.z*cB.z + zB.w*cB.w;
    p = grpsum4(p);                     // 32-dim channel dot, |p| <= 1
    float ex = __expf(p);
    float d  = rowtotal16(ex);          // softmax denom (4 channels, in-row)
    float w  = ex * __builtin_amdgcn_rcpf(d);
    aA.x += w * zA.x;  aA.y += w * zA.y;  aA.z += w * zA.z;  aA.w += w * zA.w;
    aB.x += w * zB.x;  aB.y += w * zB.y;  aB.z += w * zB.z;  aB.w += w * zB.w;
}

// ---------------------------------------------------------------------------
// GEMM + per-channel L2 normalize via MFMA fp16 (inputs cast to fp16, fp32
// accumulate; l2norm cancels the common scale error).
// Block = 64 rows (4 waves x 16 rows), full 128 cols.
// W staged fp16 in LDS, rows padded to 136 halfs (bank spread).
// A/B fragments built with the SAME k-slot formula -> result invariant to
// the HW's internal k permutation. C/D layout VERIFIED (m89/m101):
// D[row=(lane>>4)*4+j][col=lane&15] per 16-col tile.
// ---------------------------------------------------------------------------
__global__ __launch_bounds__(256)
void gemm_norm_mfma_kernel(const float* __restrict__ x, const float* __restrict__ W,
                           const float* __restrict__ b, float* __restrict__ h, int n)
{
    __shared__ _Float16 wlds[128 * 136];   // 34.8 KB

    const int tid  = threadIdx.x;
    const int wv   = tid >> 6;
    const int lane = tid & 63;
    const int lo   = lane & 15;
    const int hi   = lane >> 4;

    // stage W -> fp16 LDS (16384 elems, 64/thread, coalesced float4 reads)
    for (int t = 0; t < 16; ++t) {
        int idx = (t * 256 + tid) * 4;
        int j = idx >> 7, k = idx & 127;
        float4 w4 = *(const float4*)(W + idx);
        _Float16* dst = &wlds[j * 136 + k];
        dst[0] = (_Float16)w4.x; dst[1] = (_Float16)w4.y;
        dst[2] = (_Float16)w4.z; dst[3] = (_Float16)w4.w;
    }
    __syncthreads();

    const int rowbase = blockIdx.x * 64 + wv * 16;
    int row  = rowbase + lo;
    int rowc = row < n ? row : n - 1;

    // A-fragments: 4 K-tiles; lane holds x[row][32q + 8*hi .. +8) (RNE casts)
    half8 afrag[4];
    #pragma unroll
    for (int q = 0; q < 4; ++q) {
        const float* src = x + (size_t)rowc * 128 + q * 32 + hi * 8;
        float4 u0 = *(const float4*)src;
        float4 u1 = *(const float4*)(src + 4);
        afrag[q][0] = (_Float16)u0.x; afrag[q][1] = (_Float16)u0.y;
        afrag[q][2] = (_Float16)u0.z; afrag[q][3] = (_Float16)u0.w;
        afrag[q][4] = (_Float16)u1.x; afrag[q][5] = (_Float16)u1.y;
        afrag[q][6] = (_Float16)u1.z; afrag[q][7] = (_Float16)u1.w;
    }

    // accumulators seeded with bias (col = 16t + lo; same for all j)
    f32x4 acc[8];
    #pragma unroll
    for (int t = 0; t < 8; ++t) {
        float bb = b[t * 16 + lo];
        acc[t][0] = bb; acc[t][1] = bb; acc[t][2] = bb; acc[t][3] = bb;
    }

    // mfma: D[m][n] = sum_k x[m][k] * W[n][k]; B-frag lane holds
    // W[16t+lo][32q + 8*hi .. +8) — same k formula as A.
    #pragma unroll
    for (int q = 0; q < 4; ++q) {
        #pragma unroll
        for (int t = 0; t < 8; ++t) {
            half8 bfrag = *(const half8*)&wlds[(t * 16 + lo) * 136 + q * 32 + hi * 8];
            acc[t] = __builtin_amdgcn_mfma_f32_16x16x32_f16(afrag[q], bfrag, acc[t], 0, 0, 0);
        }
    }

    // epilogue: per-channel (32 cols = tiles 2c,2c+1) l2norm + store.
    // slot (t, j): value at row rowbase + hi*4 + j, col 16t + lo.
    #pragma unroll
    for (int c = 0; c < 4; ++c) {
        #pragma unroll
        for (int j = 0; j < 4; ++j) {
            float v0 = acc[2 * c][j];
            float v1 = acc[2 * c + 1][j];
            float ss = rowsum16(v0 * v0 + v1 * v1);
            float inv = __builtin_amdgcn_rcpf(fmaxf(sqrtf(ss), 1e-12f));
            int r = rowbase + hi * 4 + j;
            if (r < n) {
                h[(size_t)r * 128 + c * 32 + lo]      = v0 * inv;
                h[(size_t)r * 128 + c * 32 + 16 + lo] = v1 * inv;
            }
        }
    }
}

// ---------------------------------------------------------------------------
// prep: zero cnt, zero h row n (the dummy row), pre-fill padded edge_src
// with n, detect idx dtype. All independent; grid-stride over padcap.
// ---------------------------------------------------------------------------
__global__ void prep_kernel(int* __restrict__ cnt, int n,
                            float* __restrict__ h,
                            int* __restrict__ edge_src, long long padcap,
                            const int* __restrict__ raw, int* __restrict__ flag)
{
    long long i = (long long)blockIdx.x * blockDim.x + threadIdx.x;
    long long stride = (long long)gridDim.x * blockDim.x;
    for (long long k = i; k < padcap; k += stride) {
        if (k < n) cnt[k] = 0;
        if (k < 128) h[(size_t)n * 128 + k] = 0.0f;
        edge_src[k] = n;
    }
    if (i == 0) {
        int all_zero = 1;
        for (int k = 1; k < 64; k += 2)
            if (raw[k] != 0) { all_zero = 0; break; }
        *flag = all_zero;
    }
}

// hist: 4 edges per thread, vectorized index loads
__global__ void hist_kernel(const void* __restrict__ st, long long m, int n,
                            const int* __restrict__ idx64, int* __restrict__ cnt)
{
    long long e4 = ((long long)blockIdx.x * blockDim.x + threadIdx.x) * 4;
    if (e4 >= m) return;
    int is64 = *idx64;
    int cnt4 = (int)((m - e4) < 4 ? (m - e4) : 4);
    int t[4];
    if (is64) {
        const long long* p = (const long long*)st + m + e4;
        if (cnt4 == 4) {
            longlong2 a = *(const longlong2*)p;
            longlong2 c = *(const longlong2*)(p + 2);
            t[0] = (int)a.x; t[1] = (int)a.y; t[2] = (int)c.x; t[3] = (int)c.y;
        } else {
            for (int i = 0; i < cnt4; ++i) t[i] = (int)p[i];
        }
    } else {
        const int* p = (const int*)st + m + e4;
        if (cnt4 == 4) {
            int4 a = *(const int4*)p;
            t[0] = a.x; t[1] = a.y; t[2] = a.z; t[3] = a.w;
        } else {
            for (int i = 0; i < cnt4; ++i) t[i] = p[i];
        }
    }
    for (int i = 0; i < cnt4; ++i)
        if (t[i] >= 0 && t[i] < n) atomicAdd(&cnt[t[i]], 1);
}

// ---- 3-phase parallel scan over PADDED degrees (pad4) — verified r16/19 ----
__global__ __launch_bounds__(256)
void scan_partial_kernel(const int* __restrict__ cnt, int n, int chunk,
                         int* __restrict__ bsum)
{
    int b = blockIdx.x, t = threadIdx.x;
    int lo = b * chunk, hi = min(lo + chunk, n);
    int s = 0;
    for (int i = lo + t; i < hi; i += 256) s += (cnt[i] + 3) & ~3;
    __shared__ int red[256];
    red[t] = s; __syncthreads();
    for (int off = 128; off > 0; off >>= 1) {
        if (t < off) red[t] += red[t + off];
        __syncthreads();
    }
    if (t == 0) bsum[b] = red[0];
}

__global__ __launch_bounds__(256)
void scan_offsets_kernel(const int* __restrict__ bsum, int nb,
                         int* __restrict__ boff, int* __restrict__ total)
{
    __shared__ int lds[256];
    int t = threadIdx.x;
    int v = (t < nb) ? bsum[t] : 0;
    lds[t] = v; __syncthreads();
    for (int off = 1; off < 256; off <<= 1) {
        int u = (t >= off) ? lds[t - off] : 0;
        __syncthreads();
        lds[t] += u;
        __syncthreads();
    }
    if (t < nb) boff[t] = lds[t] - v;
    if (t == 255) *total = lds[255];
}

__global__ __launch_bounds__(256)
void scan_write_kernel(const int* __restrict__ cnt, int n, int chunk,
                       const int* __restrict__ boff, const int* __restrict__ total,
                       int* __restrict__ row_ptr, int* __restrict__ cursor)
{
    int b = blockIdx.x, t = threadIdx.x;
    int lo = b * chunk, hi = min(lo + chunk, n);
    __shared__ int lds[256];
    int run = boff[b];
    for (int base = lo; base < hi; base += 256) {
        int i = base + t;
        int v = (i < hi) ? ((cnt[i] + 3) & ~3) : 0;
        lds[t] = v; __syncthreads();
        for (int off = 1; off < 256; off <<= 1) {
            int u = (t >= off) ? lds[t - off] : 0;
            __syncthreads();
            lds[t] += u;
            __syncthreads();
        }
        if (i < hi) {
            int excl = run + lds[t] - v;
            row_ptr[i] = excl;
            cursor[i]  = excl;
        }
        run += lds[255];
        __syncthreads();
    }
    if (b == 0 && t == 0) row_ptr[n] = *total;
}

// scatter: 4 edges per thread, vectorized index loads
__global__ void scatter_kernel(const void* __restrict__ st, long long m, int n,
                               const int* __restrict__ idx64,
                               int* __restrict__ cursor, int* __restrict__ edge_src)
{
    long long e4 = ((long long)blockIdx.x * blockDim.x + threadIdx.x) * 4;
    if (e4 >= m) return;
    int is64 = *idx64;
    int cnt4 = (int)((m - e4) < 4 ? (m - e4) : 4);
    int t[4], s[4];
    if (is64) {
        const long long* pt = (const long long*)st + m + e4;
        const long long* ps = (const long long*)st + e4;
        for (int i = 0; i < cnt4; ++i) { t[i] = (int)pt[i]; s[i] = (int)ps[i]; }
    } else {
        const int* pt = (const int*)st + m + e4;
        const int* ps = (const int*)st + e4;
        if (cnt4 == 4) {
            int4 a = *(const int4*)pt;
            int4 c = *(const int4*)ps;
            t[0] = a.x; t[1] = a.y; t[2] = a.z; t[3] = a.w;
            s[0] = c.x; s[1] = c.y; s[2] = c.z; s[3] = c.w;
        } else {
            for (int i = 0; i < cnt4; ++i) { t[i] = pt[i]; s[i] = ps[i]; }
        }
    }
    for (int i = 0; i < cnt4; ++i) {
        if (t[i] >= 0 && t[i] < n) {
            int pos = atomicAdd(&cursor[t[i]], 1);
            edge_src[pos] = s[i];
        }
    }
}

// ---------------------------------------------------------------------------
// Routing v4 (r16/r19 verified best: 283 us): quartet layout on padded CSR,
// branch-free inner loop. Unchanged.
// ---------------------------------------------------------------------------
__global__ __launch_bounds__(64 * WPB)
void route_kernel(const float* __restrict__ h, const int* __restrict__ row_ptr,
                  const int* __restrict__ edge_src, float* __restrict__ out, int n)
{
    __shared__ float4 zlsA[WPB][CAPQ][64];
    __shared__ float4 zlsB[WPB][CAPQ][64];

    int wv   = threadIdx.x >> 6;
    int wid  = __builtin_amdgcn_readfirstlane(blockIdx.x * WPB + wv);
    int lane = threadIdx.x & 63;
    int row  = lane >> 4;
    int rl   = lane & 15;
    if (wid >= n) return;

    const float4* __restrict__ h4 = (const float4*)h;
    float4 cA = h4[(size_t)wid * 32 + rl * 2];
    float4 cB = h4[(size_t)wid * 32 + rl * 2 + 1];

    const int e0  = row_ptr[wid];
    const int np  = (row_ptr[wid + 1] - e0) >> 2;
    const int ncp = np < CAPQ ? np : CAPQ;
    const float selfm = (row == 0) ? 1.0f : 0.0f;

    float4 aA, aB;

    aA.x = cA.x*selfm; aA.y = cA.y*selfm; aA.z = cA.z*selfm; aA.w = cA.w*selfm;
    aB.x = cB.x*selfm; aB.y = cB.y*selfm; aB.z = cB.z*selfm; aB.w = cB.w*selfm;
    for (int j = 0; j < np; ++j) {
        int s = edge_src[e0 + 4 * j + row];
        float4 zA = h4[(size_t)s * 32 + rl * 2];
        float4 zB = h4[(size_t)s * 32 + rl * 2 + 1];
        if (j < ncp) {
            zlsA[wv][j][lane] = zA;
            zlsB[wv][j][lane] = zB;
        }
        quad_acc(zA, zB, cA, cB, aA, aB);
    }
    {
        aA.x = sum_x32(sum_x16(aA.x)); aA.y = sum_x32(sum_x16(aA.y));
        aA.z = sum_x32(sum_x16(aA.z)); aA.w = sum_x32(sum_x16(aA.w));
        aB.x = sum_x32(sum_x16(aB.x)); aB.y = sum_x32(sum_x16(aB.y));
        aB.z = sum_x32(sum_x16(aB.z)); aB.w = sum_x32(sum_x16(aB.w));
        float ss = aA.x*aA.x + aA.y*aA.y + aA.z*aA.z + aA.w*aA.w
                 + aB.x*aB.x + aB.y*aB.y + aB.z*aB.z + aB.w*aB.w;
        ss = grpsum4(ss);
        float inv = __builtin_amdgcn_rcpf(fmaxf(sqrtf(ss), 1e-12f));
        cA.x = aA.x*inv; cA.y = aA.y*inv; cA.z = aA.z*inv; cA.w = aA.w*inv;
        cB.x = aB.x*inv; cB.y = aB.y*inv; cB.z = aB.z*inv; cB.w = aB.w*inv;
    }

    #pragma unroll 1
    for (int it = 1; it < ROUTIT; ++it) {
        aA.x = cA.x*selfm; aA.y = cA.y*selfm; aA.z = cA.z*selfm; aA.w = cA.w*selfm;
        aB.x = cB.x*selfm; aB.y = cB.y*selfm; aB.z = cB.z*selfm; aB.w = cB.w*selfm;
        #pragma unroll 2
        for (int j = 0; j < ncp; ++j) {
            float4 zA = zlsA[wv][j][lane];
            float4 zB = zlsB[wv][j][lane];
            quad_acc(zA, zB, cA, cB, aA, aB);
        }
        for (int j = ncp; j < np; ++j) {
            int s = edge_src[e0 + 4 * j + row];
            float4 zA = h4[(size_t)s * 32 + rl * 2];
            float4 zB = h4[(size_t)s * 32 + rl * 2 + 1];
            quad_acc(zA, zB, cA, cB, aA, aB);
        }
        aA.x = sum_x32(sum_x16(aA.x)); aA.y = sum_x32(sum_x16(aA.y));
        aA.z = sum_x32(sum_x16(aA.z)); aA.w = sum_x32(sum_x16(aA.w));
        aB.x = sum_x32(sum_x16(aB.x)); aB.y = sum_x32(sum_x16(aB.y));
        aB.z = sum_x32(sum_x16(aB.z)); aB.w = sum_x32(sum_x16(aB.w));
        float ss = aA.x*aA.x + aA.y*aA.y + aA.z*aA.z + aA.w*aA.w
                 + aB.x*aB.x + aB.y*aB.y + aB.z*aB.z + aB.w*aB.w;
        ss = grpsum4(ss);
        float inv = __builtin_amdgcn_rcpf(fmaxf(sqrtf(ss), 1e-12f));
        cA.x = aA.x*inv; cA.y = aA.y*inv; cA.z = aA.z*inv; cA.w = aA.w*inv;
        cB.x = aB.x*inv; cB.y = aB.y*inv; cB.z = aB.z*inv; cB.w = aB.w*inv;
    }

    if (row == 0) {
        ((float4*)out)[(size_t)wid * 32 + rl * 2]     = cA;
        ((float4*)out)[(size_t)wid * 32 + rl * 2 + 1] = cB;
    }
}

// ---------------------------------------------------------------------------
extern "C" void kernel_launch(void* const* d_in, const int* in_sizes, int n_in,
                              void* d_out, int out_size, void* d_ws, size_t ws_size,
                              hipStream_t stream)
{
    const float* x       = (const float*)d_in[0];
    const void*  src_trg = d_in[1];
    const float* W       = (const float*)d_in[2];
    const float* b       = (const float*)d_in[3];
    float*       out     = (float*)d_out;

    int n = in_sizes[0] / 128;
    long long m = in_sizes[1] / 2;
    int chunk = (n + SCB - 1) / SCB;
    long long padcap = m + 3LL * n + 4;   // worst-case padded edge count
    long long m4 = (m + 3) / 4;

    // workspace layout (~61 MB)
    float* h        = (float*)d_ws;                      // (n+1)*128 floats
    int*   cnt      = (int*)(h + (size_t)(n + 1) * 128); // n
    int*   row_ptr  = cnt + n;                           // n+1
    int*   cursor   = row_ptr + (n + 1);                 // n
    int*   edge_src = cursor + n;                        // padcap ints
    int*   idx64    = edge_src + padcap;                 // 1 flag
    int*   bsum     = idx64 + 1;                         // SCB
    int*   boff     = bsum + SCB;                        // SCB
    int*   total    = boff + SCB;                        // 1

    hipLaunchKernelGGL(gemm_norm_mfma_kernel, dim3((n + 63) / 64), dim3(256), 0, stream,
                       x, W, b, h, n);
    hipLaunchKernelGGL(prep_kernel, dim3(2048), dim3(256), 0, stream,
                       cnt, n, h, edge_src, padcap, (const int*)src_trg, idx64);
    hipLaunchKernelGGL(hist_kernel, dim3((int)((m4 + 255) / 256)), dim3(256), 0, stream,
                       src_trg, m, n, idx64, cnt);
    hipLaunchKernelGGL(scan_partial_kernel, dim3(SCB), dim3(256), 0, stream,
                       cnt, n, chunk, bsum);
    hipLaunchKernelGGL(scan_offsets_kernel, dim3(1), dim3(256), 0, stream,
                       bsum, SCB, boff, total);
    hipLaunchKernelGGL(scan_write_kernel, dim3(SCB), dim3(256), 0, stream,
                       cnt, n, chunk, boff, total, row_ptr, cursor);
    hipLaunchKernelGGL(scatter_kernel, dim3((int)((m4 + 255) / 256)), dim3(256), 0, stream,
                       src_trg, m, n, idx64, cursor, edge_src);
    hipLaunchKernelGGL(route_kernel, dim3((n + WPB - 1) / WPB), dim3(64 * WPB), 0, stream,
                       h, row_ptr, edge_src, out, n);
}